// Round 2
// 572.450 us; speedup vs baseline: 1.0899x; 1.0899x over previous
//
#include <hip/hip_runtime.h>
#include <cstdint>
#include <cstddef>

#define B_ 8
#define S_ 4096
#define D_ 2048
#define N_ 8192
#define K_ 64
#define CH_ 64          // number of s-chunks for partial query sums
#define SC_ 64          // S_ / CH_
#define CAP_ 512        // candidate list capacity for top-k selection
#define NEG_INF (-3.402823466e+38f)

typedef float f32x4 __attribute__((ext_vector_type(4)));

// ---------------- helpers ----------------
__device__ inline float wave_reduce_sum(float v) {
#pragma unroll
    for (int off = 32; off > 0; off >>= 1) v += __shfl_down(v, off, 64);
    return v;
}

// ---------------- Kernel A: copy x -> out (non-temporal), partial masked sums over s-chunks
// grid: B_ * 2 * CH_ = 1024 blocks, 256 threads
__global__ __launch_bounds__(256) void kA(const float* __restrict__ x,
                                          const unsigned char* __restrict__ mask,
                                          float* __restrict__ out,
                                          float* __restrict__ part) {
    const int bi   = blockIdx.x;
    const int c    = bi & (CH_ - 1);
    const int half = (bi >> 6) & 1;
    const int b    = bi >> 7;
    const int t    = threadIdx.x;
    const int f4   = half * 256 + t;          // 0..511 (float4 index within D)

    const f32x4* x4  = (const f32x4*)x;
    f32x4*       o4  = (f32x4*)out;
    const unsigned char* mrow = mask + b * S_;

    f32x4 acc = {0.f, 0.f, 0.f, 0.f};
    const int s0 = c * SC_;
#pragma unroll 4
    for (int s = s0; s < s0 + SC_; ++s) {
        const int idx = (b * S_ + s) * 512 + f4;
        f32x4 v = __builtin_nontemporal_load(&x4[idx]);
        __builtin_nontemporal_store(v, &o4[idx]);
        if (mrow[s]) acc += v;
    }
    ((f32x4*)part)[(b * CH_ + c) * 512 + f4] = acc;
}

// ---------------- Kernel Q (fused A2+A3): reduce partials -> qsum[b][:]; qn[b]; last[b]
// grid: 8 blocks (one per b), 256 threads
__global__ __launch_bounds__(256) void kQ(const float* __restrict__ part,
                                          const unsigned char* __restrict__ mask,
                                          float* __restrict__ qsum,
                                          float* __restrict__ qn,
                                          int* __restrict__ lastI) {
    const int b = blockIdx.x;
    const int t = threadIdx.x;
    const float4* p4 = (const float4*)part;

    float4 a0 = make_float4(0.f, 0.f, 0.f, 0.f);
    float4 a1 = make_float4(0.f, 0.f, 0.f, 0.f);
#pragma unroll 4
    for (int c = 0; c < CH_; ++c) {
        const float4* row = p4 + (size_t)(b * CH_ + c) * 512;
        float4 x0 = row[t], x1 = row[256 + t];
        a0.x += x0.x; a0.y += x0.y; a0.z += x0.z; a0.w += x0.w;
        a1.x += x1.x; a1.y += x1.y; a1.z += x1.z; a1.w += x1.w;
    }
    float4* q4 = (float4*)qsum + (size_t)b * 512;
    q4[t]       = a0;
    q4[256 + t] = a1;

    float sq = 0.f;
    sq = fmaf(a0.x, a0.x, sq); sq = fmaf(a0.y, a0.y, sq);
    sq = fmaf(a0.z, a0.z, sq); sq = fmaf(a0.w, a0.w, sq);
    sq = fmaf(a1.x, a1.x, sq); sq = fmaf(a1.y, a1.y, sq);
    sq = fmaf(a1.z, a1.z, sq); sq = fmaf(a1.w, a1.w, sq);

    float fcnt = 0.f;
#pragma unroll
    for (int j = 0; j < 16; ++j)
        fcnt += (mask[b * S_ + j * 256 + t] != 0) ? 1.0f : 0.0f;

    sq   = wave_reduce_sum(sq);
    fcnt = wave_reduce_sum(fcnt);

    __shared__ float sv[4];
    __shared__ float sc[4];
    const int w = t >> 6, lane = t & 63;
    if (lane == 0) { sv[w] = sq; sc[w] = fcnt; }
    __syncthreads();
    if (t == 0) {
        float s = sv[0] + sv[1] + sv[2] + sv[3];
        int   c = (int)(sc[0] + sc[1] + sc[2] + sc[3] + 0.5f);
        qn[b]    = fmaxf(sqrtf(s), 1e-12f);
        lastI[b] = (c > 1 ? c : 1) - 1;
    }
}

// ---------------- Kernel B: sims[b][n] = dot(qsum_b, key_n) / (qn_b * kn_n)
// grid: 512 blocks, 256 threads (4 waves), each wave does 4 key rows
__global__ __launch_bounds__(256) void kB(const float* __restrict__ keys,
                                          const float* __restrict__ qsum,
                                          const float* __restrict__ qn,
                                          float* __restrict__ sims) {
    __shared__ float qs[B_ * D_];      // 64 KB, b-major: qs[b*D_ + d]
    const int t = threadIdx.x;
    {
        const float4* g4 = (const float4*)qsum;
        float4*       l4 = (float4*)qs;
#pragma unroll
        for (int j = 0; j < 16; ++j) l4[j * 256 + t] = g4[j * 256 + t];
    }
    __syncthreads();

    const int wv = t >> 6, lane = t & 63;
    const float4* k4  = (const float4*)keys;
    const float4* q4  = (const float4*)qs;

    for (int r = 0; r < 4; ++r) {
        const int row = blockIdx.x * 16 + wv * 4 + r;
        float kk = 0.f;
        float dots[8];
#pragma unroll
        for (int i = 0; i < 8; ++i) dots[i] = 0.f;

#pragma unroll
        for (int seg = 0; seg < 8; ++seg) {
            float4 kv = k4[row * 512 + seg * 64 + lane];
            kk = fmaf(kv.x, kv.x, kk);
            kk = fmaf(kv.y, kv.y, kk);
            kk = fmaf(kv.z, kv.z, kk);
            kk = fmaf(kv.w, kv.w, kk);
#pragma unroll
            for (int b = 0; b < 8; ++b) {
                float4 q = q4[b * 512 + seg * 64 + lane];   // lane-consecutive b128: conflict-free
                dots[b] = fmaf(kv.x, q.x,
                          fmaf(kv.y, q.y,
                          fmaf(kv.z, q.z,
                          fmaf(kv.w, q.w, dots[b]))));
            }
        }
        // wave reduction (9 scalars)
#pragma unroll
        for (int off = 32; off > 0; off >>= 1) {
            kk += __shfl_down(kk, off, 64);
#pragma unroll
            for (int i = 0; i < 8; ++i) dots[i] += __shfl_down(dots[i], off, 64);
        }
        if (lane == 0) {
            float invk = 1.0f / fmaxf(sqrtf(kk), 1e-12f);
#pragma unroll
            for (int i = 0; i < 8; ++i)
                sims[i * N_ + row] = dots[i] * invk / qn[i];
        }
    }
}

// ---------------- Kernel CD (fused top-k + softmax + gate + value gather + out add)
// Exact top-64 via histogram threshold + bitonic sort of candidates.
// grid: 8 blocks (one per b), 256 threads
__global__ __launch_bounds__(256) void kCD(const float* __restrict__ sims,
                                           const float* __restrict__ values,
                                           const int* __restrict__ lastI,
                                           float* __restrict__ out) {
    const int b = blockIdx.x;
    const int t = threadIdx.x;

    __shared__ unsigned int hist[4096];       // 12-bit ordered-uint bins
    __shared__ unsigned int segsum[256];
    __shared__ unsigned long long skeys[CAP_]; // (ordered_u << 32) | ~idx
    __shared__ unsigned int cnt;
    __shared__ int sBth;
    __shared__ float cw[K_];
    __shared__ int   cidx[K_];

    for (int i = t; i < 4096; i += 256) hist[i] = 0u;
    if (t == 0) cnt = 0u;
    __syncthreads();

    // load 32 sims per thread, build ordered-uint keys + histogram
    unsigned int u[32];
#pragma unroll
    for (int j = 0; j < 32; ++j) {
        float v = sims[b * N_ + j * 256 + t];
        unsigned int fb = __float_as_uint(v);
        u[j] = (fb & 0x80000000u) ? ~fb : (fb | 0x80000000u);
        atomicAdd(&hist[u[j] >> 20], 1u);
    }
    __syncthreads();

    // find threshold bin Bth: #(bin > Bth) < 64 <= #(bin >= Bth)
    {
        unsigned int seg = 0u;
        const int s0b = t * 16;
#pragma unroll
        for (int k2 = 0; k2 < 16; ++k2) seg += hist[s0b + k2];
        segsum[t] = seg;
    }
    __syncthreads();
    if (t == 0) {
        unsigned int acc = 0u;
        int s = 255;
        for (; s > 0; --s) {
            unsigned int ns = acc + segsum[s];
            if (ns >= 64u) break;
            acc = ns;
        }
        int bth = s * 16;
        for (int bidx = s * 16 + 15; bidx >= s * 16; --bidx) {
            unsigned int nb = acc + hist[bidx];
            if (nb >= 64u) { bth = bidx; break; }
            acc = nb;
        }
        sBth = bth;
    }
    __syncthreads();

    // gather candidates (bin >= Bth). Expected ~64-150; cap CAP_=512.
    const unsigned int bthU = (unsigned int)sBth;
#pragma unroll
    for (int j = 0; j < 32; ++j) {
        if ((u[j] >> 20) >= bthU) {
            unsigned int pos = atomicAdd(&cnt, 1u);
            if (pos < CAP_) {
                unsigned int idx = (unsigned int)(j * 256 + t);
                skeys[pos] = ((unsigned long long)u[j] << 32) | (unsigned int)(~idx);
            }
        }
    }
    __syncthreads();

    // pad with zero-keys (sort descending puts them last; cnt >= 64 guaranteed)
    {
        unsigned int c = cnt; if (c > CAP_) c = CAP_;
        for (int i = (int)c + t; i < CAP_; i += 256) skeys[i] = 0ull;
    }

    // bitonic sort CAP_ elements, descending
    for (int k = 2; k <= CAP_; k <<= 1) {
        for (int jj = k >> 1; jj > 0; jj >>= 1) {
            __syncthreads();
            for (int i0 = 0; i0 < CAP_ / 256; ++i0) {
                const int i = t + i0 * 256;
                const int ixj = i ^ jj;
                if (ixj > i) {
                    unsigned long long a  = skeys[i];
                    unsigned long long bb = skeys[ixj];
                    const bool up = ((i & k) == 0);
                    if (up ? (a < bb) : (a > bb)) { skeys[i] = bb; skeys[ixj] = a; }
                }
            }
        }
    }
    __syncthreads();

    // top-64 = skeys[0..63]; softmax + gate on wave 0
    if (t < 64) {
        unsigned long long kk = skeys[t];
        unsigned int uu = (unsigned int)(kk >> 32);
        unsigned int fb = (uu & 0x80000000u) ? (uu & 0x7fffffffu) : ~uu;
        float val = __uint_as_float(fb);
        int   idx = (int)((~(unsigned int)kk) & 0x1FFFu);

        float vmax = __shfl(val, 0, 64);
        float wgt  = expf((val - vmax) * (1.0f / 0.03f));
        float z = wgt;
#pragma unroll
        for (int off = 32; off > 0; off >>= 1) z += __shfl_down(z, off, 64);
        z = __shfl(z, 0, 64);
        const float gate = 1.0f / (1.0f + expf(-(vmax - 0.85f) * 40.0f));
        const float coef = 16.0f * gate / z;
        cw[t]   = coef * wgt;
        cidx[t] = idx;
    }
    __syncthreads();

    // fused kD: out[b, last, :] += sum_i cw_i * values[idx_i, :]
    const float4* v4 = (const float4*)values;
    float4 a0 = make_float4(0.f, 0.f, 0.f, 0.f);
    float4 a1 = make_float4(0.f, 0.f, 0.f, 0.f);
#pragma unroll 4
    for (int i = 0; i < K_; ++i) {
        const float wgt = cw[i];
        const int   n   = cidx[i];
        const float4* r = v4 + (size_t)n * 512;
        float4 x0 = r[t], x1 = r[256 + t];
        a0.x = fmaf(wgt, x0.x, a0.x); a0.y = fmaf(wgt, x0.y, a0.y);
        a0.z = fmaf(wgt, x0.z, a0.z); a0.w = fmaf(wgt, x0.w, a0.w);
        a1.x = fmaf(wgt, x1.x, a1.x); a1.y = fmaf(wgt, x1.y, a1.y);
        a1.z = fmaf(wgt, x1.z, a1.z); a1.w = fmaf(wgt, x1.w, a1.w);
    }
    const int last = lastI[b];
    float4* o4 = (float4*)out + ((size_t)(b * S_ + last)) * 512;
    float4 c0 = o4[t], c1 = o4[256 + t];
    c0.x += a0.x; c0.y += a0.y; c0.z += a0.z; c0.w += a0.w;
    c1.x += a1.x; c1.y += a1.y; c1.z += a1.z; c1.w += a1.w;
    o4[t]       = c0;
    o4[256 + t] = c1;
}

// ---------------- launcher ----------------
extern "C" void kernel_launch(void* const* d_in, const int* in_sizes, int n_in,
                              void* d_out, int out_size, void* d_ws, size_t ws_size,
                              hipStream_t stream) {
    const float*         x      = (const float*)d_in[0];
    const unsigned char* mask   = (const unsigned char*)d_in[1];
    const float*         keys   = (const float*)d_in[2];
    const float*         values = (const float*)d_in[3];
    float*               out    = (float*)d_out;

    char* ws = (char*)d_ws;
    // workspace layout (all 16B-aligned)
    float* part = (float*)(ws);                       // B*CH*D        = 4 MB
    float* qsum = (float*)(ws + 4194304);             // B*D           = 64 KB
    float* qn   = (float*)(ws + 4259840);             // B             = 32 B
    int*   last = (int*)  (ws + 4259872);             // B             = 32 B
    float* sims = (float*)(ws + 4259904);             // B*N           = 256 KB

    kA <<<dim3(B_ * 2 * CH_), dim3(256), 0, stream>>>(x, mask, out, part);
    kQ <<<dim3(B_),           dim3(256), 0, stream>>>(part, mask, qsum, qn, last);
    kB <<<dim3(N_ / 16),      dim3(256), 0, stream>>>(keys, qsum, qn, sims);
    kCD<<<dim3(B_),           dim3(256), 0, stream>>>(sims, values, last, out);
}

// Round 3
// 538.022 us; speedup vs baseline: 1.1596x; 1.0640x over previous
//
#include <hip/hip_runtime.h>
#include <cstdint>
#include <cstddef>

#define B_ 8
#define S_ 4096
#define D_ 2048
#define N_ 8192
#define K_ 64
#define CH_ 64          // number of s-chunks for partial query sums
#define SC_ 64          // S_ / CH_
#define CAP_ 512        // candidate list capacity for top-k selection
#define NEG_INF (-3.402823466e+38f)

typedef float f32x4 __attribute__((ext_vector_type(4)));

// ---------------- helpers ----------------
__device__ inline float wave_reduce_sum(float v) {
#pragma unroll
    for (int off = 32; off > 0; off >>= 1) v += __shfl_down(v, off, 64);
    return v;
}

// ---------------- Kernel A: copy x -> out (non-temporal), partial masked sums over s-chunks
// grid: B_ * 2 * CH_ = 1024 blocks, 256 threads
__global__ __launch_bounds__(256) void kA(const float* __restrict__ x,
                                          const unsigned char* __restrict__ mask,
                                          float* __restrict__ out,
                                          float* __restrict__ part) {
    const int bi   = blockIdx.x;
    const int c    = bi & (CH_ - 1);
    const int half = (bi >> 6) & 1;
    const int b    = bi >> 7;
    const int t    = threadIdx.x;
    const int f4   = half * 256 + t;          // 0..511 (float4 index within D)

    const f32x4* x4  = (const f32x4*)x;
    f32x4*       o4  = (f32x4*)out;
    const unsigned char* mrow = mask + b * S_;

    f32x4 acc = {0.f, 0.f, 0.f, 0.f};
    const int s0 = c * SC_;
#pragma unroll 4
    for (int s = s0; s < s0 + SC_; ++s) {
        const int idx = (b * S_ + s) * 512 + f4;
        f32x4 v = __builtin_nontemporal_load(&x4[idx]);
        __builtin_nontemporal_store(v, &o4[idx]);
        if (mrow[s]) acc += v;
    }
    ((f32x4*)part)[(b * CH_ + c) * 512 + f4] = acc;
}

// ---------------- Kernel Q (fused A2+A3): reduce partials -> qsum[b][:]; qn[b]; last[b]
// grid: 8 blocks (one per b), 256 threads
__global__ __launch_bounds__(256) void kQ(const float* __restrict__ part,
                                          const unsigned char* __restrict__ mask,
                                          float* __restrict__ qsum,
                                          float* __restrict__ qn,
                                          int* __restrict__ lastI) {
    const int b = blockIdx.x;
    const int t = threadIdx.x;
    const float4* p4 = (const float4*)part;

    float4 a0 = make_float4(0.f, 0.f, 0.f, 0.f);
    float4 a1 = make_float4(0.f, 0.f, 0.f, 0.f);
#pragma unroll 4
    for (int c = 0; c < CH_; ++c) {
        const float4* row = p4 + (size_t)(b * CH_ + c) * 512;
        float4 x0 = row[t], x1 = row[256 + t];
        a0.x += x0.x; a0.y += x0.y; a0.z += x0.z; a0.w += x0.w;
        a1.x += x1.x; a1.y += x1.y; a1.z += x1.z; a1.w += x1.w;
    }
    float4* q4 = (float4*)qsum + (size_t)b * 512;
    q4[t]       = a0;
    q4[256 + t] = a1;

    float sq = 0.f;
    sq = fmaf(a0.x, a0.x, sq); sq = fmaf(a0.y, a0.y, sq);
    sq = fmaf(a0.z, a0.z, sq); sq = fmaf(a0.w, a0.w, sq);
    sq = fmaf(a1.x, a1.x, sq); sq = fmaf(a1.y, a1.y, sq);
    sq = fmaf(a1.z, a1.z, sq); sq = fmaf(a1.w, a1.w, sq);

    float fcnt = 0.f;
#pragma unroll
    for (int j = 0; j < 16; ++j)
        fcnt += (mask[b * S_ + j * 256 + t] != 0) ? 1.0f : 0.0f;

    sq   = wave_reduce_sum(sq);
    fcnt = wave_reduce_sum(fcnt);

    __shared__ float sv[4];
    __shared__ float sc[4];
    const int w = t >> 6, lane = t & 63;
    if (lane == 0) { sv[w] = sq; sc[w] = fcnt; }
    __syncthreads();
    if (t == 0) {
        float s = sv[0] + sv[1] + sv[2] + sv[3];
        int   c = (int)(sc[0] + sc[1] + sc[2] + sc[3] + 0.5f);
        qn[b]    = fmaxf(sqrtf(s), 1e-12f);
        lastI[b] = (c > 1 ? c : 1) - 1;
    }
}

// ---------------- Kernel B: sims[b][n] = dot(qsum_b, key_n) / (qn_b * kn_n)
// grid: 512 blocks, 256 threads (4 waves), each wave does 4 key rows.
// Register-blocked: q fragments hoisted to VGPRs once per seg, reused over 4 rows
// (cuts LDS traffic 4x vs per-row re-read).
__global__ __launch_bounds__(256) void kB(const float* __restrict__ keys,
                                          const float* __restrict__ qsum,
                                          const float* __restrict__ qn,
                                          float* __restrict__ sims) {
    __shared__ float qs[B_ * D_];      // 64 KB, b-major: qs[b*D_ + d]
    const int t = threadIdx.x;
    {
        const float4* g4 = (const float4*)qsum;
        float4*       l4 = (float4*)qs;
#pragma unroll
        for (int j = 0; j < 16; ++j) l4[j * 256 + t] = g4[j * 256 + t];
    }
    __syncthreads();

    const int wv = t >> 6, lane = t & 63;
    const float4* k4  = (const float4*)keys;
    const float4* q4  = (const float4*)qs;
    const int row0 = blockIdx.x * 16 + wv * 4;

    float kk[4];
    float dots[4][8];
#pragma unroll
    for (int r = 0; r < 4; ++r) {
        kk[r] = 0.f;
#pragma unroll
        for (int b = 0; b < 8; ++b) dots[r][b] = 0.f;
    }

#pragma unroll
    for (int seg = 0; seg < 8; ++seg) {
        float4 qb[8];
#pragma unroll
        for (int b = 0; b < 8; ++b)
            qb[b] = q4[b * 512 + seg * 64 + lane];   // lane-consecutive b128: conflict-free
#pragma unroll
        for (int r = 0; r < 4; ++r) {
            float4 kv = k4[(size_t)(row0 + r) * 512 + seg * 64 + lane];
            kk[r] = fmaf(kv.x, kv.x, kk[r]);
            kk[r] = fmaf(kv.y, kv.y, kk[r]);
            kk[r] = fmaf(kv.z, kv.z, kk[r]);
            kk[r] = fmaf(kv.w, kv.w, kk[r]);
#pragma unroll
            for (int b = 0; b < 8; ++b) {
                dots[r][b] = fmaf(kv.x, qb[b].x,
                             fmaf(kv.y, qb[b].y,
                             fmaf(kv.z, qb[b].z,
                             fmaf(kv.w, qb[b].w, dots[r][b]))));
            }
        }
    }

    // wave reduction (36 scalars)
#pragma unroll
    for (int off = 32; off > 0; off >>= 1) {
#pragma unroll
        for (int r = 0; r < 4; ++r) {
            kk[r] += __shfl_down(kk[r], off, 64);
#pragma unroll
            for (int b = 0; b < 8; ++b)
                dots[r][b] += __shfl_down(dots[r][b], off, 64);
        }
    }
    if (lane == 0) {
#pragma unroll
        for (int r = 0; r < 4; ++r) {
            float invk = 1.0f / fmaxf(sqrtf(kk[r]), 1e-12f);
#pragma unroll
            for (int b = 0; b < 8; ++b)
                sims[b * N_ + row0 + r] = dots[r][b] * invk / qn[b];
        }
    }
}

// ---------------- Kernel CD (fused top-k + softmax + gate + value gather + out add)
// Exact top-64 via histogram threshold + bitonic sort of candidates.
// grid: 8 blocks (one per b), 512 threads (widened for gather ILP)
__global__ __launch_bounds__(512) void kCD(const float* __restrict__ sims,
                                           const float* __restrict__ values,
                                           const int* __restrict__ lastI,
                                           float* __restrict__ out) {
    const int b = blockIdx.x;
    const int t = threadIdx.x;

    __shared__ unsigned int hist[4096];       // 12-bit ordered-uint bins
    __shared__ unsigned int segsum[256];
    __shared__ unsigned long long skeys[CAP_]; // (ordered_u << 32) | ~idx
    __shared__ unsigned int cnt;
    __shared__ int sBth;
    __shared__ float cw[K_];
    __shared__ int   cidx[K_];

    for (int i = t; i < 4096; i += 512) hist[i] = 0u;
    if (t == 0) cnt = 0u;
    __syncthreads();

    // load 16 sims per thread, build ordered-uint keys + histogram
    unsigned int u[16];
#pragma unroll
    for (int j = 0; j < 16; ++j) {
        float v = sims[b * N_ + j * 512 + t];
        unsigned int fb = __float_as_uint(v);
        u[j] = (fb & 0x80000000u) ? ~fb : (fb | 0x80000000u);
        atomicAdd(&hist[u[j] >> 20], 1u);
    }
    __syncthreads();

    // find threshold bin Bth: #(bin > Bth) < 64 <= #(bin >= Bth)
    if (t < 256) {
        unsigned int seg = 0u;
        const int s0b = t * 16;
#pragma unroll
        for (int k2 = 0; k2 < 16; ++k2) seg += hist[s0b + k2];
        segsum[t] = seg;
    }
    __syncthreads();
    if (t == 0) {
        unsigned int acc = 0u;
        int s = 255;
        for (; s > 0; --s) {
            unsigned int ns = acc + segsum[s];
            if (ns >= 64u) break;
            acc = ns;
        }
        int bth = s * 16;
        for (int bidx = s * 16 + 15; bidx >= s * 16; --bidx) {
            unsigned int nb = acc + hist[bidx];
            if (nb >= 64u) { bth = bidx; break; }
            acc = nb;
        }
        sBth = bth;
    }
    __syncthreads();

    // gather candidates (bin >= Bth). Expected ~64-150; cap CAP_=512.
    const unsigned int bthU = (unsigned int)sBth;
#pragma unroll
    for (int j = 0; j < 16; ++j) {
        if ((u[j] >> 20) >= bthU) {
            unsigned int pos = atomicAdd(&cnt, 1u);
            if (pos < CAP_) {
                unsigned int idx = (unsigned int)(j * 512 + t);
                skeys[pos] = ((unsigned long long)u[j] << 32) | (unsigned int)(~idx);
            }
        }
    }
    __syncthreads();

    // pad with zero-keys (sort descending puts them last; cnt >= 64 guaranteed)
    {
        unsigned int c = cnt; if (c > CAP_) c = CAP_;
        for (int i = (int)c + t; i < CAP_; i += 512) skeys[i] = 0ull;
    }

    // bitonic sort CAP_ elements, descending (512 threads: one slot each)
    for (int k = 2; k <= CAP_; k <<= 1) {
        for (int jj = k >> 1; jj > 0; jj >>= 1) {
            __syncthreads();
            {
                const int i = t;
                const int ixj = i ^ jj;
                if (ixj > i) {
                    unsigned long long a  = skeys[i];
                    unsigned long long bb = skeys[ixj];
                    const bool up = ((i & k) == 0);
                    if (up ? (a < bb) : (a > bb)) { skeys[i] = bb; skeys[ixj] = a; }
                }
            }
        }
    }
    __syncthreads();

    // top-64 = skeys[0..63]; softmax + gate on wave 0
    if (t < 64) {
        unsigned long long kk = skeys[t];
        unsigned int uu = (unsigned int)(kk >> 32);
        unsigned int fb = (uu & 0x80000000u) ? (uu & 0x7fffffffu) : ~uu;
        float val = __uint_as_float(fb);
        int   idx = (int)((~(unsigned int)kk) & 0x1FFFu);

        float vmax = __shfl(val, 0, 64);
        float wgt  = expf((val - vmax) * (1.0f / 0.03f));
        float z = wgt;
#pragma unroll
        for (int off = 32; off > 0; off >>= 1) z += __shfl_down(z, off, 64);
        z = __shfl(z, 0, 64);
        const float gate = 1.0f / (1.0f + expf(-(vmax - 0.85f) * 40.0f));
        const float coef = 16.0f * gate / z;
        cw[t]   = coef * wgt;
        cidx[t] = idx;
    }
    __syncthreads();

    // fused kD: out[b, last, :] += sum_i cw_i * values[idx_i, :]
    // 512 threads: one float4 (d-slice) per thread, 64 gather iterations.
    const float4* v4 = (const float4*)values;
    float4 a0 = make_float4(0.f, 0.f, 0.f, 0.f);
#pragma unroll 8
    for (int i = 0; i < K_; ++i) {
        const float wgt = cw[i];
        const int   n   = cidx[i];
        float4 x0 = v4[(size_t)n * 512 + t];
        a0.x = fmaf(wgt, x0.x, a0.x); a0.y = fmaf(wgt, x0.y, a0.y);
        a0.z = fmaf(wgt, x0.z, a0.z); a0.w = fmaf(wgt, x0.w, a0.w);
    }
    const int last = lastI[b];
    float4* o4 = (float4*)out + ((size_t)(b * S_ + last)) * 512;
    float4 c0 = o4[t];
    c0.x += a0.x; c0.y += a0.y; c0.z += a0.z; c0.w += a0.w;
    o4[t] = c0;
}

// ---------------- launcher ----------------
extern "C" void kernel_launch(void* const* d_in, const int* in_sizes, int n_in,
                              void* d_out, int out_size, void* d_ws, size_t ws_size,
                              hipStream_t stream) {
    const float*         x      = (const float*)d_in[0];
    const unsigned char* mask   = (const unsigned char*)d_in[1];
    const float*         keys   = (const float*)d_in[2];
    const float*         values = (const float*)d_in[3];
    float*               out    = (float*)d_out;

    char* ws = (char*)d_ws;
    // workspace layout (all 16B-aligned)
    float* part = (float*)(ws);                       // B*CH*D        = 4 MB
    float* qsum = (float*)(ws + 4194304);             // B*D           = 64 KB
    float* qn   = (float*)(ws + 4259840);             // B             = 32 B
    int*   last = (int*)  (ws + 4259872);             // B             = 32 B
    float* sims = (float*)(ws + 4259904);             // B*N           = 256 KB

    kA <<<dim3(B_ * 2 * CH_), dim3(256), 0, stream>>>(x, mask, out, part);
    kQ <<<dim3(B_),           dim3(256), 0, stream>>>(part, mask, qsum, qn, last);
    kB <<<dim3(N_ / 16),      dim3(256), 0, stream>>>(keys, qsum, qn, sims);
    kCD<<<dim3(B_),           dim3(512), 0, stream>>>(sims, values, last, out);
}